// Round 1
// baseline (1597.456 us; speedup 1.0000x reference)
//
#include <hip/hip_runtime.h>

// AttentivePooling, two-pass restructure.
// N=1048576 nodes, HID=256, G=2048 graphs, batch sorted.
//
// Previous fused online-softmax kernel ran ~670us (=25% of HBM) because its
// 135KB LDS forced 1 block/CU and the per-tile barrier pipeline (cvt -> MFMA
// -> wave0 softmax -> accumulate) serialized with nothing to hide behind.
//
// New plan (weights only need per-graph scalars, so decouple):
//   1) score_kernel: stream x (1.07GB), bf16 MFMA scoring, write scores[N].
//      W1^T fragments held in registers (one 16-col tile per wave, cross-wave
//      LDS reduce) -> LDS 71.7KB -> 2 blocks/CU.
//   2) seg_kernel: per-graph max and 1/sum(exp) over scores (L2-hot, ~5us).
//   3) pool2_kernel: stream x again, out += exp(s-m)*x, barrier-free loop at
//      32 waves/CU, one block per graph (sorted batch), no atomics, f32 math.
// Total HBM ~2.16GB -> ~400-440us vs ~670us fused.

#define HID   256
#define HHID  128
#define TILE  128          // nodes per score tile
#define BLK   512          // threads per block (8 waves)
#define PITCH 264          // bf16 elems per LDS row: 256+8 pad (132 dw, %32=4)

typedef __attribute__((ext_vector_type(8))) short short8;
typedef __attribute__((ext_vector_type(4))) float f32x4;

__device__ __forceinline__ unsigned short f2bf(float f) {
  unsigned u = __builtin_bit_cast(unsigned, f);
  u += 0x7fffu + ((u >> 16) & 1u);           // RNE
  return (unsigned short)(u >> 16);
}

// ---------------- prep: W1^T -> bf16 in ws, and segment starts ----------------
__global__ void prep_kernel(const float* __restrict__ W1,   // [256][128]
                            const int* __restrict__ batch,  // [N], sorted
                            unsigned short* __restrict__ w1t, // [128][256] bf16
                            int* __restrict__ starts,       // [G+1]
                            int n, int g) {
  int tid = blockIdx.x * blockDim.x + threadIdx.x;
  if (tid < HID * HHID) {
    int k = tid / HHID, j = tid % HHID;
    w1t[j * HID + k] = f2bf(W1[tid]);
  }
  if (tid < n) {
    int b = batch[tid];
    int prev = (tid == 0) ? -1 : batch[tid - 1];
    for (int q = prev + 1; q <= b; ++q) starts[q] = tid;
    if (tid == n - 1)
      for (int q = b + 1; q <= g; ++q) starts[q] = n;
  }
}

// ---------------- pass 1: scores = tanh(x@W1+b1)@W2 + b2 ----------------
// Grid-stride over 128-node tiles. Wave w owns hidden cols [16w,16w+16):
// its 8 K-fragments of W1^T stay in registers for the whole kernel.
__global__ __launch_bounds__(BLK, 4) void score_kernel(
    const float* __restrict__ x,            // [N][256]
    const unsigned short* __restrict__ w1t, // [128][256] bf16
    const float* __restrict__ b1,           // [128]
    const float* __restrict__ W2,           // [128]
    const float* __restrict__ b2,           // [1]
    float* __restrict__ scores,             // [N]
    int n)
{
  __shared__ __align__(16) unsigned short lds_x[TILE * PITCH]; // 67.6 KB
  __shared__ float lds_part[8][TILE];                          // 4 KB

  const int t    = threadIdx.x;
  const int lane = t & 63;
  const int wave = t >> 6;
  const int col  = wave * 16 + (lane & 15);   // this wave's hidden col
  const int kq   = (lane >> 4) << 3;          // k-quad offset
  const int hi   = lane >> 4;

  // stationary B fragments: W1^T rows = hidden cols (L2-hot, 64KB shared)
  short8 bfrag[8];
#pragma unroll
  for (int s = 0; s < 8; ++s)
    bfrag[s] = *(const short8*)(w1t + col * HID + s * 32 + kq);
  const float b1v = b1[col];
  const float w2v = W2[col];
  const float b2v = b2[0];

  const int ntiles = (n + TILE - 1) / TILE;

  for (int tt = blockIdx.x; tt < ntiles; tt += gridDim.x) {
    const int base = tt * TILE;

    __syncthreads();   // prior tile fully consumed (lds_x + lds_part)

    // ---- stage 128x256 f32 -> bf16 LDS tile ----
#pragma unroll
    for (int k2 = 0; k2 < 8; ++k2) {
      int item = t + k2 * BLK;        // 0..4095
      int row  = item >> 5;
      int c8   = (item & 31) << 3;
      int node = base + row;
      f32x4 a, b;
      if (node < n) {
        const float* p = x + (size_t)node * HID + c8;
        a = *(const f32x4*)p;
        b = *(const f32x4*)(p + 4);
      } else {
        a = (f32x4){0.f, 0.f, 0.f, 0.f};
        b = a;
      }
      short8 v;
#pragma unroll
      for (int q = 0; q < 4; ++q) v[q]     = (short)f2bf(a[q]);
#pragma unroll
      for (int q = 0; q < 4; ++q) v[q + 4] = (short)f2bf(b[q]);
      *(short8*)(&lds_x[row * PITCH + c8]) = v;
    }
    __syncthreads();   // lds_x ready

    // ---- scoring: wave w computes its 16 cols for all 8 row-tiles ----
#pragma unroll
    for (int rt = 0; rt < 8; ++rt) {
      const int arow = rt * 16 + (lane & 15);
      f32x4 acc = {0.f, 0.f, 0.f, 0.f};
#pragma unroll
      for (int s = 0; s < 8; ++s) {
        short8 afrag = *(const short8*)(&lds_x[arow * PITCH + s * 32 + kq]);
        acc = __builtin_amdgcn_mfma_f32_16x16x32_bf16(afrag, bfrag[s], acc, 0, 0, 0);
      }
      // acc[r]: node row = rt*16 + hi*4 + r, col = this lane's col
      float p[4];
#pragma unroll
      for (int r = 0; r < 4; ++r) {
        float h  = acc[r] + b1v;
        float e2 = __expf(2.f * h);          // tanh via exp
        float th = (e2 - 1.f) / (e2 + 1.f);
        p[r] = th * w2v;
      }
      // butterfly over the 16 cols (low 4 lane bits)
#pragma unroll
      for (int m = 1; m <= 8; m <<= 1) {
#pragma unroll
        for (int r = 0; r < 4; ++r) p[r] += __shfl_xor(p[r], m, 64);
      }
      if ((lane & 15) == 0) {
#pragma unroll
        for (int r = 0; r < 4; ++r)
          lds_part[wave][rt * 16 + hi * 4 + r] = p[r];
      }
    }
    __syncthreads();   // partials ready

    // ---- reduce 8 wave-partials, write scores ----
    if (t < TILE) {
      float s = b2v;
#pragma unroll
      for (int w = 0; w < 8; ++w) s += lds_part[w][t];
      int node = base + t;
      if (node < n) scores[node] = s;
    }
  }
}

// ---------------- pass 2a: per-graph max and inverse denom ----------------
__global__ void seg_kernel(const float* __restrict__ scores,
                           const int* __restrict__ starts,
                           float* __restrict__ mg,
                           float* __restrict__ invl)
{
  const int g    = blockIdx.x;
  const int lane = threadIdx.x;        // 64 threads
  const int s0 = starts[g], s1 = starts[g + 1];

  float mx = -1e30f;
  for (int i = s0 + lane; i < s1; i += 64) mx = fmaxf(mx, scores[i]);
#pragma unroll
  for (int m = 1; m <= 32; m <<= 1) mx = fmaxf(mx, __shfl_xor(mx, m, 64));

  float sum = 0.f;
  for (int i = s0 + lane; i < s1; i += 64) sum += __expf(scores[i] - mx);
#pragma unroll
  for (int m = 1; m <= 32; m <<= 1) sum += __shfl_xor(sum, m, 64);

  if (lane == 0) {
    mg[g]   = mx;
    invl[g] = (s1 > s0) ? 1.f / sum : 0.f;
  }
}

// ---------------- pass 2b: out[g] = sum_n exp(s-m)*x * invl ----------------
// One block per graph. Barrier-free streaming accumulate, f32 throughout.
// thread t: channels 8*(t&31).., node slice t>>5 (stride 16).
__global__ __launch_bounds__(BLK, 8) void pool2_kernel(
    const float* __restrict__ x,        // [N][256]
    const float* __restrict__ scores,   // [N]
    const int* __restrict__ starts,     // [G+1]
    const float* __restrict__ mg,       // [G]
    const float* __restrict__ invl,     // [G]
    float* __restrict__ out)            // [G][256]
{
  __shared__ __align__(16) float red[16 * HID];   // 16 KB

  const int t  = threadIdx.x;
  const int g  = blockIdx.x;
  const int start = starts[g], end = starts[g + 1];
  const float m  = mg[g];
  const float il = invl[g];
  const int cg = (t & 31) << 3;
  const int sl = t >> 5;               // 0..15

  f32x4 oa = {0.f, 0.f, 0.f, 0.f};
  f32x4 ob = {0.f, 0.f, 0.f, 0.f};

  for (int nd = start + sl; nd < end; nd += 16) {
    float w = __expf(scores[nd] - m);
    const float* p = x + (size_t)nd * HID + cg;
    f32x4 a = *(const f32x4*)p;
    f32x4 b = *(const f32x4*)(p + 4);
#pragma unroll
    for (int j = 0; j < 4; ++j) {
      oa[j] = fmaf(w, a[j], oa[j]);
      ob[j] = fmaf(w, b[j], ob[j]);
    }
  }

  *(f32x4*)(&red[sl * HID + cg])     = oa;
  *(f32x4*)(&red[sl * HID + cg + 4]) = ob;
  __syncthreads();
#pragma unroll
  for (int st = 8; st >= 1; st >>= 1) {
    if (sl < st) {
#pragma unroll
      for (int j = 0; j < 8; ++j)
        red[sl * HID + cg + j] += red[(sl + st) * HID + cg + j];
    }
    __syncthreads();
  }
  if (t < 64) {
    f32x4 o;
#pragma unroll
    for (int j = 0; j < 4; ++j) o[j] = red[t * 4 + j] * il;
    *(f32x4*)(out + (size_t)g * HID + t * 4) = o;
  }
}

extern "C" void kernel_launch(void* const* d_in, const int* in_sizes, int n_in,
                              void* d_out, int out_size, void* d_ws, size_t ws_size,
                              hipStream_t stream) {
  const float* x     = (const float*)d_in[0];
  const int*   batch = (const int*)d_in[1];
  const float* W1    = (const float*)d_in[2];
  const float* b1    = (const float*)d_in[3];
  const float* W2    = (const float*)d_in[4];
  const float* b2    = (const float*)d_in[5];
  float* out = (float*)d_out;

  const int n = in_sizes[0] / HID;   // 1048576
  const int g = out_size / HID;      // 2048

  // workspace layout (16B aligned):
  //   w1t   : 128*256 bf16  = 65536 B   @ 0
  //   starts: (G+1) int     = 8196 B    @ 65536 (reserve 8448)
  //   scores: N f32         = 4 MB      @ 73984
  //   mg    : G f32                     @ 73984 + 4n
  //   invl  : G f32
  unsigned short* w1t = (unsigned short*)d_ws;
  int*   starts = (int*)((char*)d_ws + 65536);
  float* scores = (float*)((char*)d_ws + 65536 + 8448);
  float* mg     = scores + n;
  float* invl   = mg + g;

  prep_kernel<<<(n + 255) / 256, 256, 0, stream>>>(W1, batch, w1t, starts, n, g);
  score_kernel<<<2048, BLK, 0, stream>>>(x, w1t, b1, W2, b2, scores, n);
  seg_kernel<<<g, 64, 0, stream>>>(scores, starts, mg, invl);
  pool2_kernel<<<g, BLK, 0, stream>>>(x, scores, starts, mg, invl, out);
}